// Round 2
// baseline (3295.792 us; speedup 1.0000x reference)
//
#include <hip/hip_runtime.h>

typedef __bf16 bf16x8 __attribute__((ext_vector_type(8)));
typedef float f32x4 __attribute__((ext_vector_type(4)));
typedef unsigned int u32x4 __attribute__((ext_vector_type(4)));
typedef u32x4 u32x4a __attribute__((may_alias));   // alias-safe 16B punning

#define NITER 8  // m-tiles (16 points) per wave in the MFMA kernel

__device__ inline float b2f(unsigned short u) {
    unsigned int x = ((unsigned int)u) << 16;
    float f;
    __builtin_memcpy(&f, &x, 4);
    return f;
}
__device__ inline unsigned short f2b(float f) {
    unsigned int x;
    __builtin_memcpy(&x, &f, 4);
    unsigned int r = (x + 0x7FFFu + ((x >> 16) & 1u)) >> 16;  // RNE
    return (unsigned short)r;
}
__device__ inline float softplus_f(float x) {   // fast (bf16 tolerance)
    return fmaxf(x, 0.f) + __logf(1.f + __expf(-fabsf(x)));
}
__device__ inline float softplus_p(float x) {   // precise (f32 tolerance)
    return fmaxf(x, 0.f) + log1pf(expf(-fabsf(x)));
}
__device__ inline bf16x8 as_bf16x8(u32x4 v) { return __builtin_bit_cast(bf16x8, v); }

// dtype sniff: read 64 raw u16 words of occ_b0. True bf16 biases are bounded by
// 1/sqrt(32)~0.18; f32 data's mantissa-low words decode to |v|>=1 w.p. ~0.5 each.
__device__ inline bool data_is_bf16(const ushort* p) {
    bool ok = true;
#pragma unroll
    for (int i = 0; i < 64; i++) {
        float v = b2f(p[i]);
        ok = ok && (fabsf(v) < 1.0f);   // NaN compares false -> classified f32
    }
    return ok;
}

// ============================ bf16 MFMA kernel ============================
// Fragment layouts (verified m89/m97): A[m=lane&15][k=(lane>>4)*8+j],
// B[k=(lane>>4)*8+j][n=lane&15], C/D col=lane&15,row=(lane>>4)*4+reg.
__global__ __launch_bounds__(256) void net_bf16(
    const ushort* __restrict__ emb, const ushort* __restrict__ dir,
    const ushort* __restrict__ oW0, const ushort* __restrict__ ob0,
    const ushort* __restrict__ oW1, const ushort* __restrict__ ob1,
    const ushort* __restrict__ oW2, const ushort* __restrict__ ob2,
    const ushort* __restrict__ rW0, const ushort* __restrict__ rb0,
    const ushort* __restrict__ rW1, const ushort* __restrict__ rb1,
    const ushort* __restrict__ rW2, const ushort* __restrict__ rb2,
    const ushort* __restrict__ rlat, const int* __restrict__ lidx,
    ushort* __restrict__ out, int n)
{
    if (!data_is_bf16(ob0)) return;

    __shared__ __align__(16) ushort s_w[36 * 64 * 8];   // 36,864 B fragment-major weights
    __shared__ __align__(16) float  s_bias[288];
    __shared__ __align__(16) ushort s_x[4][16 * 104];   // emb|dir|feat A-layout, stride 104
    __shared__ __align__(16) ushort s_h[4][16 * 72];    // hidden, stride 72

    const int tid = threadIdx.x;

    // ---- one-time weight swizzle into fragment-major LDS ----
    // frag bases: occ0:0(Nt4,Kt1) occ1:4(4,2) occ2:12(1,2) rgb0:14(4,3) rgb1:26(4,2) rgb2:34(1,2)
    for (int s = tid; s < 36 * 64; s += 256) {
        const int frag = s >> 6, lane = s & 63;
        const int qq = lane >> 4, cc = lane & 15;
        const ushort* W;
        int ldn = 64, nt = 0, kt = 0;
        bool isr0 = false, isr2 = false;
        if (frag < 4)       { W = oW0; nt = frag; kt = 0; }
        else if (frag < 12) { W = oW1; int f = frag - 4;  nt = f >> 1; kt = f & 1; }
        else if (frag < 14) { W = oW2; ldn = 16; nt = 0; kt = frag - 12; }
        else if (frag < 26) { W = rW0; int f = frag - 14; nt = f / 3; kt = f - nt * 3; isr0 = true; }
        else if (frag < 34) { W = rW1; int f = frag - 26; nt = f >> 1; kt = f & 1; }
        else                { W = rW2; ldn = 3; nt = 0; kt = frag - 34; isr2 = true; }
        const int nn = nt * 16 + cc;
        __align__(16) ushort vals[8];
#pragma unroll
        for (int j = 0; j < 8; j++) {
            int k = kt * 32 + qq * 8 + j;
            ushort v = 0;
            if (isr0) {
                // packed x: k<32 emb(rows 0..31), 32..58 dir(rows 32..58), 64..78 feat(rows 59..73)
                int ks = -1;
                if (k < 59) ks = k;
                else if (k >= 64 && k < 79) ks = k - 5;
                if (ks >= 0) v = W[ks * 64 + nn];
            } else if (isr2) {
                if (nn < 3) v = W[k * 3 + nn];
            } else {
                v = W[k * ldn + nn];
            }
            vals[j] = v;
        }
        *(u32x4a*)&s_w[s * 8] = *(const u32x4a*)vals;
    }
    // biases (f32): [0]occ_b0 [64]occ_b1 [128]occ_b2 [144]rgb_b1 [208]rgb_b2(pad16) [224]rgb_b0'
    for (int i = tid; i < 224; i += 256) {
        float v;
        if (i < 64)       v = b2f(ob0[i]);
        else if (i < 128) v = b2f(ob1[i - 64]);
        else if (i < 144) v = b2f(ob2[i - 128]);
        else if (i < 208) v = b2f(rb1[i - 144]);
        else              v = (i - 208 < 3) ? b2f(rb2[i - 208]) : 0.f;
        s_bias[i] = v;
    }
    if (tid < 64) {
        // rgb_b0' = rgb_b0 + latent @ rgb_W0[74:202]  (latent identical for all points)
        float acc = b2f(rb0[tid]);
        const int li = ((unsigned)lidx[0]) % 100u;
        const ushort* lat = rlat + (size_t)li * 128;
        for (int k = 0; k < 128; k++)
            acc += b2f(lat[k]) * b2f(rW0[(74 + k) * 64 + tid]);
        s_bias[224 + tid] = acc;
    }
    __syncthreads();

    const int wave = tid >> 6, lane = tid & 63, q = lane >> 4, c = lane & 15;
    ushort* xw = s_x[wave];
    ushort* hw = s_h[wave];

    // zero padding once: cols 59..63 (dir pad) and 79..95 (feat pad) — never overwritten
    for (int f = lane; f < 80; f += 64) {
        int pt = f / 5, e = f - pt * 5;
        xw[pt * 104 + 59 + e] = 0;
    }
    for (int f = lane; f < 16 * 17; f += 64) {
        int pt = f / 17, e = f - pt * 17;
        xw[pt * 104 + 79 + e] = 0;
    }

    for (int it = 0; it < NITER; ++it) {
        const long p0 = ((long)blockIdx.x * NITER + it) * 64 + wave * 16;

        // ---- stage inputs into A-layout LDS ----
        {   // emb: 16 pts x 32, one 16B chunk per lane
            u32x4 v = *(const u32x4a*)(emb + p0 * 32 + lane * 8);
            *(u32x4a*)&xw[(lane >> 2) * 104 + (lane & 3) * 8] = v;
        }
        for (int f = lane; f < 432; f += 64) {  // dir: 16 x 27
            int pt = f / 27, e = f - pt * 27;
            xw[pt * 104 + 32 + e] = dir[p0 * 27 + f];
        }

        // ---- occ layer 0: K=32, out 64, softplus ----
        {
            bf16x8 a0 = as_bf16x8(*(const u32x4a*)&xw[c * 104 + q * 8]);
#pragma unroll
            for (int nt = 0; nt < 4; ++nt) {
                bf16x8 b = as_bf16x8(*(const u32x4a*)&s_w[((0 + nt) * 64 + lane) * 8]);
                float bs = s_bias[nt * 16 + c];
                f32x4 acc = {bs, bs, bs, bs};
                acc = __builtin_amdgcn_mfma_f32_16x16x32_bf16(a0, b, acc, 0, 0, 0);
#pragma unroll
                for (int r = 0; r < 4; r++)
                    hw[(q * 4 + r) * 72 + nt * 16 + c] = f2b(softplus_f(acc[r]));
            }
        }
        // ---- occ layer 1: K=64, out 64, softplus ----
        {
            bf16x8 a[2];
#pragma unroll
            for (int kt = 0; kt < 2; kt++)
                a[kt] = as_bf16x8(*(const u32x4a*)&hw[c * 72 + kt * 32 + q * 8]);
#pragma unroll
            for (int nt = 0; nt < 4; ++nt) {
                float bs = s_bias[64 + nt * 16 + c];
                f32x4 acc = {bs, bs, bs, bs};
#pragma unroll
                for (int kt = 0; kt < 2; kt++) {
                    bf16x8 b = as_bf16x8(*(const u32x4a*)&s_w[((4 + nt * 2 + kt) * 64 + lane) * 8]);
                    acc = __builtin_amdgcn_mfma_f32_16x16x32_bf16(a[kt], b, acc, 0, 0, 0);
                }
#pragma unroll
                for (int r = 0; r < 4; r++)
                    hw[(q * 4 + r) * 72 + nt * 16 + c] = f2b(softplus_f(acc[r]));
            }
        }
        // ---- occ layer 2: K=64, out 16 (col0=occ-pre, 1..15 feature) ----
        float occv[4] = {0.f, 0.f, 0.f, 0.f};
        {
            bf16x8 a[2];
#pragma unroll
            for (int kt = 0; kt < 2; kt++)
                a[kt] = as_bf16x8(*(const u32x4a*)&hw[c * 72 + kt * 32 + q * 8]);
            float bs = s_bias[128 + c];
            f32x4 acc = {bs, bs, bs, bs};
#pragma unroll
            for (int kt = 0; kt < 2; kt++) {
                bf16x8 b = as_bf16x8(*(const u32x4a*)&s_w[((12 + kt) * 64 + lane) * 8]);
                acc = __builtin_amdgcn_mfma_f32_16x16x32_bf16(a[kt], b, acc, 0, 0, 0);
            }
            if (c == 0) {
#pragma unroll
                for (int r = 0; r < 4; r++)
                    occv[r] = 1.f - __expf(-softplus_f(acc[r]));
            } else {
#pragma unroll
                for (int r = 0; r < 4; r++)
                    xw[(q * 4 + r) * 104 + 63 + c] = f2b(acc[r]);  // feat col 64+(c-1)
            }
        }
        // ---- rgb layer 0: K=96, out 64, softplus, bias=rgb_b0' ----
        {
            bf16x8 a[3];
#pragma unroll
            for (int kt = 0; kt < 3; kt++)
                a[kt] = as_bf16x8(*(const u32x4a*)&xw[c * 104 + kt * 32 + q * 8]);
#pragma unroll
            for (int nt = 0; nt < 4; ++nt) {
                float bs = s_bias[224 + nt * 16 + c];
                f32x4 acc = {bs, bs, bs, bs};
#pragma unroll
                for (int kt = 0; kt < 3; kt++) {
                    bf16x8 b = as_bf16x8(*(const u32x4a*)&s_w[((14 + nt * 3 + kt) * 64 + lane) * 8]);
                    acc = __builtin_amdgcn_mfma_f32_16x16x32_bf16(a[kt], b, acc, 0, 0, 0);
                }
#pragma unroll
                for (int r = 0; r < 4; r++)
                    hw[(q * 4 + r) * 72 + nt * 16 + c] = f2b(softplus_f(acc[r]));
            }
        }
        // ---- rgb layer 1: K=64, out 64, softplus ----
        {
            bf16x8 a[2];
#pragma unroll
            for (int kt = 0; kt < 2; kt++)
                a[kt] = as_bf16x8(*(const u32x4a*)&hw[c * 72 + kt * 32 + q * 8]);
#pragma unroll
            for (int nt = 0; nt < 4; ++nt) {
                float bs = s_bias[144 + nt * 16 + c];
                f32x4 acc = {bs, bs, bs, bs};
#pragma unroll
                for (int kt = 0; kt < 2; kt++) {
                    bf16x8 b = as_bf16x8(*(const u32x4a*)&s_w[((26 + nt * 2 + kt) * 64 + lane) * 8]);
                    acc = __builtin_amdgcn_mfma_f32_16x16x32_bf16(a[kt], b, acc, 0, 0, 0);
                }
#pragma unroll
                for (int r = 0; r < 4; r++)
                    hw[(q * 4 + r) * 72 + nt * 16 + c] = f2b(softplus_f(acc[r]));
            }
        }
        // ---- rgb layer 2: K=64, out 3 (sigmoid) + writes ----
        {
            bf16x8 a[2];
#pragma unroll
            for (int kt = 0; kt < 2; kt++)
                a[kt] = as_bf16x8(*(const u32x4a*)&hw[c * 72 + kt * 32 + q * 8]);
            float bs = s_bias[208 + c];
            f32x4 acc = {bs, bs, bs, bs};
#pragma unroll
            for (int kt = 0; kt < 2; kt++) {
                bf16x8 b = as_bf16x8(*(const u32x4a*)&s_w[((34 + kt) * 64 + lane) * 8]);
                acc = __builtin_amdgcn_mfma_f32_16x16x32_bf16(a[kt], b, acc, 0, 0, 0);
            }
            const long pr = p0 + q * 4;
            if (c < 3) {
#pragma unroll
                for (int r = 0; r < 4; r++) {
                    float v = 1.f / (1.f + __expf(-acc[r]));
                    out[(pr + r) * 4 + c] = f2b(v);
                }
            }
            if (c == 0) {
#pragma unroll
                for (int r = 0; r < 4; r++) {
                    ushort ov = f2b(occv[r]);
                    out[(pr + r) * 4 + 3] = ov;          // raw[:,3] = occ
                    out[(long)4 * n + pr + r] = ov;      // occ output
                }
            }
        }
    }
}

// ============================ f32 scalar kernel ============================
// One wave per point; lane = output-neuron index; broadcasts via __shfl.
__global__ __launch_bounds__(256) void net_f32(
    const float* __restrict__ emb, const float* __restrict__ dir,
    const float* __restrict__ oW0, const float* __restrict__ ob0,
    const float* __restrict__ oW1, const float* __restrict__ ob1,
    const float* __restrict__ oW2, const float* __restrict__ ob2,
    const float* __restrict__ rW0, const float* __restrict__ rb0,
    const float* __restrict__ rW1, const float* __restrict__ rb1,
    const float* __restrict__ rW2, const float* __restrict__ rb2,
    const float* __restrict__ rlat, const int* __restrict__ lidx,
    float* __restrict__ out, int n)
{
    if (data_is_bf16((const ushort*)ob0)) return;
    const int lane = threadIdx.x & 63;
    const int wid = blockIdx.x * 4 + (threadIdx.x >> 6);
    const int nw = gridDim.x * 4;
    const int li = ((unsigned)lidx[0]) % 100u;
    const float* lat = rlat + (size_t)li * 128;
    const float lat0 = lat[lane], lat1 = lat[64 + lane];

    for (long p = wid; p < n; p += nw) {
        float e = (lane < 32) ? emb[p * 32 + lane] : 0.f;
        float d = (lane < 27) ? dir[p * 27 + lane] : 0.f;
        // occ0
        float s = ob0[lane];
        for (int k = 0; k < 32; k++) s = fmaf(__shfl(e, k), oW0[k * 64 + lane], s);
        float h = softplus_p(s);
        // occ1
        s = ob1[lane];
        for (int k = 0; k < 64; k++) s = fmaf(__shfl(h, k), oW1[k * 64 + lane], s);
        float g = softplus_p(s);
        // occ2 (valid for lane<16)
        s = ob2[lane & 15];
        for (int k = 0; k < 64; k++) s = fmaf(__shfl(g, k), oW2[k * 16 + (lane & 15)], s);
        float hid = s;
        float occ = -expm1f(-softplus_p(__shfl(hid, 0)));
        // rgb0: x = [emb(0..31), dir(32..58), feat(59..73), latent(74..201)]
        s = rb0[lane];
        for (int k = 0; k < 32; k++)  s = fmaf(__shfl(e, k),        rW0[k * 64 + lane], s);
        for (int k = 0; k < 27; k++)  s = fmaf(__shfl(d, k),        rW0[(32 + k) * 64 + lane], s);
        for (int k = 0; k < 15; k++)  s = fmaf(__shfl(hid, 1 + k),  rW0[(59 + k) * 64 + lane], s);
        for (int k = 0; k < 64; k++)  s = fmaf(__shfl(lat0, k),     rW0[(74 + k) * 64 + lane], s);
        for (int k = 0; k < 64; k++)  s = fmaf(__shfl(lat1, k),     rW0[(138 + k) * 64 + lane], s);
        h = softplus_p(s);
        // rgb1
        s = rb1[lane];
        for (int k = 0; k < 64; k++) s = fmaf(__shfl(h, k), rW1[k * 64 + lane], s);
        g = softplus_p(s);
        // rgb2 (valid for lane<3)
        int c = (lane < 3) ? lane : 0;
        s = rb2[c];
        for (int k = 0; k < 64; k++) s = fmaf(__shfl(g, k), rW2[k * 3 + c], s);
        float rgb = 1.f / (1.f + expf(-s));
        if (lane < 3) out[p * 4 + lane] = rgb;
        if (lane == 0) { out[p * 4 + 3] = occ; out[(long)4 * n + p] = occ; }
    }
}

extern "C" void kernel_launch(void* const* d_in, const int* in_sizes, int n_in,
                              void* d_out, int out_size, void* d_ws, size_t ws_size,
                              hipStream_t stream) {
    const int n = in_sizes[0] / 32;  // N = 524288
    // bf16 hypothesis: MFMA kernel (exactly one of the two kernels runs, by data sniff)
    net_bf16<<<n / 512, 256, 0, stream>>>(
        (const ushort*)d_in[0], (const ushort*)d_in[1],
        (const ushort*)d_in[2], (const ushort*)d_in[3],
        (const ushort*)d_in[4], (const ushort*)d_in[5],
        (const ushort*)d_in[6], (const ushort*)d_in[7],
        (const ushort*)d_in[8], (const ushort*)d_in[9],
        (const ushort*)d_in[10], (const ushort*)d_in[11],
        (const ushort*)d_in[12], (const ushort*)d_in[13],
        (const ushort*)d_in[14], (const int*)d_in[15],
        (ushort*)d_out, n);
    // f32 hypothesis: scalar wave-per-point kernel
    net_f32<<<2048, 256, 0, stream>>>(
        (const float*)d_in[0], (const float*)d_in[1],
        (const float*)d_in[2], (const float*)d_in[3],
        (const float*)d_in[4], (const float*)d_in[5],
        (const float*)d_in[6], (const float*)d_in[7],
        (const float*)d_in[8], (const float*)d_in[9],
        (const float*)d_in[10], (const float*)d_in[11],
        (const float*)d_in[12], (const float*)d_in[13],
        (const float*)d_in[14], (const int*)d_in[15],
        (float*)d_out, n);
}

// Round 3
// 307.593 us; speedup vs baseline: 10.7148x; 10.7148x over previous
//
#include <hip/hip_runtime.h>

typedef __bf16 bf16x8 __attribute__((ext_vector_type(8)));
typedef float f32x4 __attribute__((ext_vector_type(4)));
typedef unsigned int u32x4 __attribute__((ext_vector_type(4)));
typedef u32x4 u32x4a __attribute__((may_alias));
typedef f32x4 f32x4a __attribute__((may_alias));

#define NITER 8  // 16-point m-tiles per wave; 512 points per block

__device__ inline unsigned short f2b(float f) {  // f32 -> bf16 RNE
    unsigned int x;
    __builtin_memcpy(&x, &f, 4);
    unsigned int r = (x + 0x7FFFu + ((x >> 16) & 1u)) >> 16;
    return (unsigned short)r;
}
__device__ inline float softplus_f(float x) {
    return fmaxf(x, 0.f) + __logf(1.f + __expf(-fabsf(x)));
}
__device__ inline bf16x8 as_bf16x8(u32x4 v) { return __builtin_bit_cast(bf16x8, v); }

// ws layout: [0..287] f32 biases | byte 1152: ushort frag-major weights 36*64*8
// bias map: [0]ob0 [64]ob1 [128]ob2 [144]rb1 [208]rb2(pad->16) [224]rgb_b0'(folded latent)
// frag bases: occ0:0(Nt4,Kt1) occ1:4(4,2) occ2:12(1,2) rgb0:14(4,3) rgb1:26(4,2) rgb2:34(1,2)
// frag layout: lane l holds B[k=kt*32+(l>>4)*8+j][n=nt*16+(l&15)], j=0..7

__global__ __launch_bounds__(256) void prep_weights(
    const float* __restrict__ oW0, const float* __restrict__ ob0,
    const float* __restrict__ oW1, const float* __restrict__ ob1,
    const float* __restrict__ oW2, const float* __restrict__ ob2,
    const float* __restrict__ rW0, const float* __restrict__ rb0,
    const float* __restrict__ rW1, const float* __restrict__ rb1,
    const float* __restrict__ rW2, const float* __restrict__ rb2,
    const float* __restrict__ rlat, const int* __restrict__ lidx,
    float* __restrict__ wsf, ushort* __restrict__ wsw)
{
    const int tid = threadIdx.x;
    // biases (f32, full precision)
    for (int i = tid; i < 224; i += 256) {
        float v;
        if (i < 64)       v = ob0[i];
        else if (i < 128) v = ob1[i - 64];
        else if (i < 144) v = ob2[i - 128];
        else if (i < 208) v = rb1[i - 144];
        else              v = (i - 208 < 3) ? rb2[i - 208] : 0.f;
        wsf[i] = v;
    }
    if (tid < 64) {  // rgb_b0' = rgb_b0 + latent @ rgb_W0[74:202]  (f32)
        float acc = rb0[tid];
        const float* lat = rlat + (size_t)lidx[0] * 128;
        for (int k = 0; k < 128; k++)
            acc = fmaf(lat[k], rW0[(74 + k) * 64 + tid], acc);
        wsf[224 + tid] = acc;
    }
    // fragment-major weight table (f32 -> bf16)
    for (int s = tid; s < 36 * 64; s += 256) {
        const int frag = s >> 6, lane = s & 63;
        const int qq = lane >> 4, cc = lane & 15;
        const float* W;
        int ldn = 64, nt = 0, kt = 0;
        bool isr0 = false, isr2 = false;
        if (frag < 4)       { W = oW0; nt = frag; kt = 0; }
        else if (frag < 12) { W = oW1; int f = frag - 4;  nt = f >> 1; kt = f & 1; }
        else if (frag < 14) { W = oW2; ldn = 16; nt = 0; kt = frag - 12; }
        else if (frag < 26) { W = rW0; int f = frag - 14; nt = f / 3; kt = f - nt * 3; isr0 = true; }
        else if (frag < 34) { W = rW1; int f = frag - 26; nt = f >> 1; kt = f & 1; }
        else                { W = rW2; ldn = 3; nt = 0; kt = frag - 34; isr2 = true; }
        const int nn = nt * 16 + cc;
        __align__(16) ushort vals[8];
#pragma unroll
        for (int j = 0; j < 8; j++) {
            int k = kt * 32 + qq * 8 + j;
            float v = 0.f;
            if (isr0) {
                // packed x rows: k<32 emb(0..31), 32..58 dir(rows 32..58), 64..78 feat(rows 59..73)
                int ks = -1;
                if (k < 59) ks = k;
                else if (k >= 64 && k < 79) ks = k - 5;
                if (ks >= 0) v = W[ks * 64 + nn];
            } else if (isr2) {
                if (nn < 3) v = W[k * 3 + nn];
            } else {
                v = W[k * ldn + nn];
            }
            vals[j] = f2b(v);
        }
        *(u32x4a*)&wsw[s * 8] = *(const u32x4a*)vals;
    }
}

// Fragment layouts (verified m89/m97): A[m=lane&15][k=(lane>>4)*8+j],
// B[k=(lane>>4)*8+j][n=lane&15], C/D col=lane&15, row=(lane>>4)*4+reg.
__global__ __launch_bounds__(256) void net_mfma(
    const float* __restrict__ emb, const float* __restrict__ dir,
    const float* __restrict__ wsf, const ushort* __restrict__ wsw,
    float* __restrict__ out, int n)
{
    __shared__ __align__(16) ushort s_w[36 * 64 * 8];   // 36,864 B
    __shared__ __align__(16) float  s_bias[288];
    __shared__ __align__(16) ushort s_x[4][16 * 104];   // emb|dir|feat A-layout, stride 104
    __shared__ __align__(16) ushort s_h[4][16 * 72];    // hidden, stride 72

    const int tid = threadIdx.x;
    // coalesced load of pre-swizzled weights + biases
    for (int i = tid; i < 36 * 64; i += 256)
        *(u32x4a*)&s_w[i * 8] = *(const u32x4a*)(wsw + i * 8);
    for (int i = tid; i < 288; i += 256)
        s_bias[i] = wsf[i];
    __syncthreads();

    const int wave = tid >> 6, lane = tid & 63, q = lane >> 4, c = lane & 15;
    ushort* xw = s_x[wave];
    ushort* hw = s_h[wave];

    // zero padding once: cols 59..63 (dir pad) and 79..95 (feat pad)
    for (int f = lane; f < 80; f += 64) {
        int pt = f / 5, e = f - pt * 5;
        xw[pt * 104 + 59 + e] = 0;
    }
    for (int f = lane; f < 16 * 17; f += 64) {
        int pt = f / 17, e = f - pt * 17;
        xw[pt * 104 + 79 + e] = 0;
    }

    for (int it = 0; it < NITER; ++it) {
        const long p0 = ((long)blockIdx.x * NITER + it) * 64 + wave * 16;

        // ---- stage inputs (f32 -> bf16) into A-layout LDS ----
        {   // emb: 16 pts x 32; lane converts 8 consecutive floats (fully coalesced)
            const float* ep = emb + p0 * 32 + (long)lane * 8;
            f32x4 v0 = *(const f32x4a*)ep;
            f32x4 v1 = *(const f32x4a*)(ep + 4);
            __align__(16) ushort vals[8];
#pragma unroll
            for (int j = 0; j < 4; j++) { vals[j] = f2b(v0[j]); vals[4 + j] = f2b(v1[j]); }
            *(u32x4a*)&xw[(lane >> 2) * 104 + (lane & 3) * 8] = *(const u32x4a*)vals;
        }
        for (int f = lane; f < 432; f += 64) {  // dir: 16 x 27
            int pt = f / 27, e = f - pt * 27;
            xw[pt * 104 + 32 + e] = f2b(dir[p0 * 27 + f]);
        }

        // ---- occ layer 0: K=32, out 64, softplus ----
        {
            bf16x8 a0 = as_bf16x8(*(const u32x4a*)&xw[c * 104 + q * 8]);
#pragma unroll
            for (int nt = 0; nt < 4; ++nt) {
                bf16x8 b = as_bf16x8(*(const u32x4a*)&s_w[((0 + nt) * 64 + lane) * 8]);
                float bs = s_bias[nt * 16 + c];
                f32x4 acc = {bs, bs, bs, bs};
                acc = __builtin_amdgcn_mfma_f32_16x16x32_bf16(a0, b, acc, 0, 0, 0);
#pragma unroll
                for (int r = 0; r < 4; r++)
                    hw[(q * 4 + r) * 72 + nt * 16 + c] = f2b(softplus_f(acc[r]));
            }
        }
        // ---- occ layer 1: K=64, out 64, softplus ----
        {
            bf16x8 a[2];
#pragma unroll
            for (int kt = 0; kt < 2; kt++)
                a[kt] = as_bf16x8(*(const u32x4a*)&hw[c * 72 + kt * 32 + q * 8]);
#pragma unroll
            for (int nt = 0; nt < 4; ++nt) {
                float bs = s_bias[64 + nt * 16 + c];
                f32x4 acc = {bs, bs, bs, bs};
#pragma unroll
                for (int kt = 0; kt < 2; kt++) {
                    bf16x8 b = as_bf16x8(*(const u32x4a*)&s_w[((4 + nt * 2 + kt) * 64 + lane) * 8]);
                    acc = __builtin_amdgcn_mfma_f32_16x16x32_bf16(a[kt], b, acc, 0, 0, 0);
                }
#pragma unroll
                for (int r = 0; r < 4; r++)
                    hw[(q * 4 + r) * 72 + nt * 16 + c] = f2b(softplus_f(acc[r]));
            }
        }
        // ---- occ layer 2: K=64, out 16 (col0 -> occ, cols 1..15 -> feature) ----
        float occv[4] = {0.f, 0.f, 0.f, 0.f};
        {
            bf16x8 a[2];
#pragma unroll
            for (int kt = 0; kt < 2; kt++)
                a[kt] = as_bf16x8(*(const u32x4a*)&hw[c * 72 + kt * 32 + q * 8]);
            float bs = s_bias[128 + c];
            f32x4 acc = {bs, bs, bs, bs};
#pragma unroll
            for (int kt = 0; kt < 2; kt++) {
                bf16x8 b = as_bf16x8(*(const u32x4a*)&s_w[((12 + kt) * 64 + lane) * 8]);
                acc = __builtin_amdgcn_mfma_f32_16x16x32_bf16(a[kt], b, acc, 0, 0, 0);
            }
            if (c == 0) {
#pragma unroll
                for (int r = 0; r < 4; r++)
                    occv[r] = 1.f - __expf(-softplus_f(acc[r]));
            } else {
#pragma unroll
                for (int r = 0; r < 4; r++)
                    xw[(q * 4 + r) * 104 + 63 + c] = f2b(acc[r]);  // feat col 64+(c-1)
            }
        }
        // ---- rgb layer 0: K=96, out 64, softplus, bias = folded rgb_b0' ----
        {
            bf16x8 a[3];
#pragma unroll
            for (int kt = 0; kt < 3; kt++)
                a[kt] = as_bf16x8(*(const u32x4a*)&xw[c * 104 + kt * 32 + q * 8]);
#pragma unroll
            for (int nt = 0; nt < 4; ++nt) {
                float bs = s_bias[224 + nt * 16 + c];
                f32x4 acc = {bs, bs, bs, bs};
#pragma unroll
                for (int kt = 0; kt < 3; kt++) {
                    bf16x8 b = as_bf16x8(*(const u32x4a*)&s_w[((14 + nt * 3 + kt) * 64 + lane) * 8]);
                    acc = __builtin_amdgcn_mfma_f32_16x16x32_bf16(a[kt], b, acc, 0, 0, 0);
                }
#pragma unroll
                for (int r = 0; r < 4; r++)
                    hw[(q * 4 + r) * 72 + nt * 16 + c] = f2b(softplus_f(acc[r]));
            }
        }
        // ---- rgb layer 1: K=64, out 64, softplus ----
        {
            bf16x8 a[2];
#pragma unroll
            for (int kt = 0; kt < 2; kt++)
                a[kt] = as_bf16x8(*(const u32x4a*)&hw[c * 72 + kt * 32 + q * 8]);
#pragma unroll
            for (int nt = 0; nt < 4; ++nt) {
                float bs = s_bias[144 + nt * 16 + c];
                f32x4 acc = {bs, bs, bs, bs};
#pragma unroll
                for (int kt = 0; kt < 2; kt++) {
                    bf16x8 b = as_bf16x8(*(const u32x4a*)&s_w[((26 + nt * 2 + kt) * 64 + lane) * 8]);
                    acc = __builtin_amdgcn_mfma_f32_16x16x32_bf16(a[kt], b, acc, 0, 0, 0);
                }
#pragma unroll
                for (int r = 0; r < 4; r++)
                    hw[(q * 4 + r) * 72 + nt * 16 + c] = f2b(softplus_f(acc[r]));
            }
        }
        // ---- rgb layer 2: K=64, out 3 (sigmoid) + writes (f32) ----
        {
            bf16x8 a[2];
#pragma unroll
            for (int kt = 0; kt < 2; kt++)
                a[kt] = as_bf16x8(*(const u32x4a*)&hw[c * 72 + kt * 32 + q * 8]);
            float bs = s_bias[208 + c];
            f32x4 acc = {bs, bs, bs, bs};
#pragma unroll
            for (int kt = 0; kt < 2; kt++) {
                bf16x8 b = as_bf16x8(*(const u32x4a*)&s_w[((34 + kt) * 64 + lane) * 8]);
                acc = __builtin_amdgcn_mfma_f32_16x16x32_bf16(a[kt], b, acc, 0, 0, 0);
            }
            const long pr = p0 + q * 4;
            if (c < 3) {
#pragma unroll
                for (int r = 0; r < 4; r++) {
                    float v = 1.f / (1.f + __expf(-acc[r]));
                    out[(pr + r) * 4 + c] = v;
                }
            }
            if (c == 0) {
#pragma unroll
                for (int r = 0; r < 4; r++) {
                    out[(pr + r) * 4 + 3] = occv[r];     // raw[:,3] = occ
                    out[(long)4 * n + pr + r] = occv[r]; // occ output
                }
            }
        }
    }
}

extern "C" void kernel_launch(void* const* d_in, const int* in_sizes, int n_in,
                              void* d_out, int out_size, void* d_ws, size_t ws_size,
                              hipStream_t stream) {
    const int n = in_sizes[0] / 32;  // N = 524288
    float*  wsf = (float*)d_ws;
    ushort* wsw = (ushort*)((char*)d_ws + 1152);
    prep_weights<<<1, 256, 0, stream>>>(
        (const float*)d_in[2], (const float*)d_in[3],
        (const float*)d_in[4], (const float*)d_in[5],
        (const float*)d_in[6], (const float*)d_in[7],
        (const float*)d_in[8], (const float*)d_in[9],
        (const float*)d_in[10], (const float*)d_in[11],
        (const float*)d_in[12], (const float*)d_in[13],
        (const float*)d_in[14], (const int*)d_in[15],
        wsf, wsw);
    net_mfma<<<n / 512, 256, 0, stream>>>(
        (const float*)d_in[0], (const float*)d_in[1],
        wsf, wsw, (float*)d_out, n);
}

// Round 4
// 235.501 us; speedup vs baseline: 13.9948x; 1.3061x over previous
//
#include <hip/hip_runtime.h>

typedef __bf16 bf16x8 __attribute__((ext_vector_type(8)));
typedef float f32x4 __attribute__((ext_vector_type(4)));
typedef unsigned int u32x4 __attribute__((ext_vector_type(4)));
typedef unsigned int u32x2 __attribute__((ext_vector_type(2)));
typedef u32x4 u32x4a __attribute__((may_alias));
typedef u32x2 u32x2a __attribute__((may_alias));
typedef f32x4 f32x4a __attribute__((may_alias));

#define NITER 8  // iters per wave; 512-thread block => 8 waves * 16 pts * 8 = 1024 pts/block

__device__ inline unsigned short f2b(float f) {  // f32 -> bf16 RNE (scalar)
    unsigned int x;
    __builtin_memcpy(&x, &f, 4);
    unsigned int r = (x + 0x7FFFu + ((x >> 16) & 1u)) >> 16;
    return (unsigned short)r;
}
__device__ inline unsigned int cvt_pk_bf16(float lo, float hi) {  // packed f32x2 -> bf16x2
    unsigned int r;
    asm("v_cvt_pk_bf16_f32 %0, %1, %2" : "=v"(r) : "v"(lo), "v"(hi));
    return r;
}
__device__ inline float softplus_f(float x) {
    return fmaxf(x, 0.f) + __logf(1.f + __expf(-fabsf(x)));
}
__device__ inline bf16x8 as_bf16x8(u32x4 v) { return __builtin_bit_cast(bf16x8, v); }

// ws layout: [0..287] f32 biases | byte 1152: ushort frag-major weights 36*64*8
// bias map: [0]ob0 [64]ob1 [128]ob2 [144]rb1 [208]rb2(pad->16) [224]rgb_b0'(folded latent)
// frag bases: occ0:0(Nt4,Kt1) occ1:4(4,2) occ2:12(1,2) rgb0:14(4,3) rgb1:26(4,2) rgb2:34(1,2)
// frag: lane l holds W[k=kt*32+(l>>4)*8+j][n=nt*16+(l&15)] == A-layout of W^T (m=l&15 -> out_local)

__global__ __launch_bounds__(256) void prep_weights(
    const float* __restrict__ oW0, const float* __restrict__ ob0,
    const float* __restrict__ oW1, const float* __restrict__ ob1,
    const float* __restrict__ oW2, const float* __restrict__ ob2,
    const float* __restrict__ rW0, const float* __restrict__ rb0,
    const float* __restrict__ rW1, const float* __restrict__ rb1,
    const float* __restrict__ rW2, const float* __restrict__ rb2,
    const float* __restrict__ rlat, const int* __restrict__ lidx,
    float* __restrict__ wsf, ushort* __restrict__ wsw)
{
    const int tid = threadIdx.x;
    for (int i = tid; i < 224; i += 256) {
        float v;
        if (i < 64)       v = ob0[i];
        else if (i < 128) v = ob1[i - 64];
        else if (i < 144) v = ob2[i - 128];
        else if (i < 208) v = rb1[i - 144];
        else              v = (i - 208 < 3) ? rb2[i - 208] : 0.f;
        wsf[i] = v;
    }
    if (tid < 64) {  // rgb_b0' = rgb_b0 + latent @ rgb_W0[74:202]  (f32)
        float acc = rb0[tid];
        const float* lat = rlat + (size_t)lidx[0] * 128;
        for (int k = 0; k < 128; k++)
            acc = fmaf(lat[k], rW0[(74 + k) * 64 + tid], acc);
        wsf[224 + tid] = acc;
    }
    for (int s = tid; s < 36 * 64; s += 256) {
        const int frag = s >> 6, lane = s & 63;
        const int qq = lane >> 4, cc = lane & 15;
        const float* W;
        int ldn = 64, nt = 0, kt = 0;
        bool isr0 = false, isr2 = false;
        if (frag < 4)       { W = oW0; nt = frag; kt = 0; }
        else if (frag < 12) { W = oW1; int f = frag - 4;  nt = f >> 1; kt = f & 1; }
        else if (frag < 14) { W = oW2; ldn = 16; nt = 0; kt = frag - 12; }
        else if (frag < 26) { W = rW0; int f = frag - 14; nt = f / 3; kt = f - nt * 3; isr0 = true; }
        else if (frag < 34) { W = rW1; int f = frag - 26; nt = f >> 1; kt = f & 1; }
        else                { W = rW2; ldn = 3; nt = 0; kt = frag - 34; isr2 = true; }
        const int nn = nt * 16 + cc;
        __align__(16) ushort vals[8];
#pragma unroll
        for (int j = 0; j < 8; j++) {
            int k = kt * 32 + qq * 8 + j;
            float v = 0.f;
            if (isr0) {
                // packed x rows: k<32 emb, 32..58 dir, 64..78 feat(src rows 59..73)
                int ks = -1;
                if (k < 59) ks = k;
                else if (k >= 64 && k < 79) ks = k - 5;
                if (ks >= 0) v = W[ks * 64 + nn];
            } else if (isr2) {
                if (nn < 3) v = W[k * 3 + nn];
            } else {
                v = W[k * ldn + nn];
            }
            vals[j] = f2b(v);
        }
        *(u32x4a*)&wsw[s * 8] = *(const u32x4a*)vals;
    }
}

// Transposed-compute kernel: D = W^T_tile · X^T_tile  (row=out, col=point).
// Lane (q=l>>4, c=l&15) holds outs nt*16+q*4+{0..3} of point c -> packed b64 writes.
__global__ __launch_bounds__(512, 4) void net_mfma(
    const float* __restrict__ emb, const float* __restrict__ dir,
    const float* __restrict__ wsf, const ushort* __restrict__ wsw,
    float* __restrict__ out, int n)
{
    __shared__ __align__(16) ushort s_w[36 * 64 * 8];    // 36,864 B
    __shared__ __align__(16) float  s_bias[288];         //  1,152 B
    __shared__ __align__(16) ushort s_h[8][16 * 72];     // 18,432 B  activations, ld=72
    __shared__ __align__(16) ushort s_feat[8][16 * 24];  //  6,144 B  feature, ld=24

    const int tid = threadIdx.x;
    for (int i = tid; i < 36 * 64; i += 512)
        *(u32x4a*)&s_w[i * 8] = *(const u32x4a*)(wsw + i * 8);
    for (int i = tid; i < 288; i += 512)
        s_bias[i] = wsf[i];
    __syncthreads();

    const int wave = tid >> 6, lane = tid & 63, q = lane >> 4, c = lane & 15;
    ushort* hw = s_h[wave];
    ushort* fw = s_feat[wave];
    if (lane < 16) fw[lane * 24 + 15] = 0;  // slot 15 (feat pad) stays zero forever

    for (int it = 0; it < NITER; ++it) {
        const long p0 = (long)blockIdx.x * 1024 + it * 128 + wave * 16;  // +c = point

        // ---- input B-fragments straight from global ----
        bf16x8 x_emb, x_dir;
        {
            const float* ep = emb + (p0 + c) * 32 + q * 8;
            f32x4 e0 = *(const f32x4a*)ep;
            f32x4 e1 = *(const f32x4a*)(ep + 4);
            u32x4 pk = {cvt_pk_bf16(e0[0], e0[1]), cvt_pk_bf16(e0[2], e0[3]),
                        cvt_pk_bf16(e1[0], e1[1]), cvt_pk_bf16(e1[2], e1[3])};
            x_emb = as_bf16x8(pk);
        }
        {
            const float* dp = dir + (p0 + c) * 27;
            float dv[8];
#pragma unroll
            for (int j = 0; j < 8; j++) {
                int kl = q * 8 + j;
                dv[j] = (kl < 27) ? dp[kl] : 0.f;
            }
            u32x4 pk = {cvt_pk_bf16(dv[0], dv[1]), cvt_pk_bf16(dv[2], dv[3]),
                        cvt_pk_bf16(dv[4], dv[5]), cvt_pk_bf16(dv[6], dv[7])};
            x_dir = as_bf16x8(pk);
        }

        // ---- occ layer 0: K=32 (emb), out 64 ----
#pragma unroll
        for (int nt = 0; nt < 4; ++nt) {
            f32x4 acc = *(const f32x4a*)&s_bias[0 + nt * 16 + q * 4];
            acc = __builtin_amdgcn_mfma_f32_16x16x32_bf16(
                as_bf16x8(*(const u32x4a*)&s_w[((0 + nt) * 64 + lane) * 8]), x_emb, acc, 0, 0, 0);
            u32x2 pk = {cvt_pk_bf16(softplus_f(acc[0]), softplus_f(acc[1])),
                        cvt_pk_bf16(softplus_f(acc[2]), softplus_f(acc[3]))};
            *(u32x2a*)&hw[c * 72 + nt * 16 + q * 4] = pk;
        }
        // ---- occ layer 1: K=64, out 64 ----
        {
            bf16x8 h0 = as_bf16x8(*(const u32x4a*)&hw[c * 72 + 0 + q * 8]);
            bf16x8 h1 = as_bf16x8(*(const u32x4a*)&hw[c * 72 + 32 + q * 8]);
#pragma unroll
            for (int nt = 0; nt < 4; ++nt) {
                f32x4 acc = *(const f32x4a*)&s_bias[64 + nt * 16 + q * 4];
                acc = __builtin_amdgcn_mfma_f32_16x16x32_bf16(
                    as_bf16x8(*(const u32x4a*)&s_w[((4 + nt * 2 + 0) * 64 + lane) * 8]), h0, acc, 0, 0, 0);
                acc = __builtin_amdgcn_mfma_f32_16x16x32_bf16(
                    as_bf16x8(*(const u32x4a*)&s_w[((4 + nt * 2 + 1) * 64 + lane) * 8]), h1, acc, 0, 0, 0);
                u32x2 pk = {cvt_pk_bf16(softplus_f(acc[0]), softplus_f(acc[1])),
                            cvt_pk_bf16(softplus_f(acc[2]), softplus_f(acc[3]))};
                *(u32x2a*)&hw[c * 72 + nt * 16 + q * 4] = pk;
            }
        }
        // ---- occ layer 2: K=64, out 16 (out0 -> occ, outs 1..15 -> feature) ----
        float occv;
        {
            bf16x8 h0 = as_bf16x8(*(const u32x4a*)&hw[c * 72 + 0 + q * 8]);
            bf16x8 h1 = as_bf16x8(*(const u32x4a*)&hw[c * 72 + 32 + q * 8]);
            f32x4 acc = *(const f32x4a*)&s_bias[128 + q * 4];
            acc = __builtin_amdgcn_mfma_f32_16x16x32_bf16(
                as_bf16x8(*(const u32x4a*)&s_w[(12 * 64 + lane) * 8]), h0, acc, 0, 0, 0);
            acc = __builtin_amdgcn_mfma_f32_16x16x32_bf16(
                as_bf16x8(*(const u32x4a*)&s_w[(13 * 64 + lane) * 8]), h1, acc, 0, 0, 0);
            occv = 1.f - __expf(-softplus_f(acc[0]));  // meaningful on q==0 lanes
#pragma unroll
            for (int r = 0; r < 4; r++) {
                int o = q * 4 + r;
                if (o > 0) fw[c * 24 + o - 1] = f2b(acc[r]);  // feature is linear
            }
        }
        // ---- rgb layer 0: K=96 (emb|dir|feat), out 64, bias = folded rgb_b0' ----
        {
            u32x4 rawf = *(const u32x4a*)&fw[c * 24 + q * 8];
            if (q >= 2) rawf = u32x4{0, 0, 0, 0};   // k-local 16..31 of feat tile = 0
            bf16x8 x_feat = as_bf16x8(rawf);
#pragma unroll
            for (int nt = 0; nt < 4; ++nt) {
                f32x4 acc = *(const f32x4a*)&s_bias[224 + nt * 16 + q * 4];
                acc = __builtin_amdgcn_mfma_f32_16x16x32_bf16(
                    as_bf16x8(*(const u32x4a*)&s_w[((14 + nt * 3 + 0) * 64 + lane) * 8]), x_emb, acc, 0, 0, 0);
                acc = __builtin_amdgcn_mfma_f32_16x16x32_bf16(
                    as_bf16x8(*(const u32x4a*)&s_w[((14 + nt * 3 + 1) * 64 + lane) * 8]), x_dir, acc, 0, 0, 0);
                acc = __builtin_amdgcn_mfma_f32_16x16x32_bf16(
                    as_bf16x8(*(const u32x4a*)&s_w[((14 + nt * 3 + 2) * 64 + lane) * 8]), x_feat, acc, 0, 0, 0);
                u32x2 pk = {cvt_pk_bf16(softplus_f(acc[0]), softplus_f(acc[1])),
                            cvt_pk_bf16(softplus_f(acc[2]), softplus_f(acc[3]))};
                *(u32x2a*)&hw[c * 72 + nt * 16 + q * 4] = pk;
            }
        }
        // ---- rgb layer 1: K=64, out 64 ----
        {
            bf16x8 h0 = as_bf16x8(*(const u32x4a*)&hw[c * 72 + 0 + q * 8]);
            bf16x8 h1 = as_bf16x8(*(const u32x4a*)&hw[c * 72 + 32 + q * 8]);
#pragma unroll
            for (int nt = 0; nt < 4; ++nt) {
                f32x4 acc = *(const f32x4a*)&s_bias[144 + nt * 16 + q * 4];
                acc = __builtin_amdgcn_mfma_f32_16x16x32_bf16(
                    as_bf16x8(*(const u32x4a*)&s_w[((26 + nt * 2 + 0) * 64 + lane) * 8]), h0, acc, 0, 0, 0);
                acc = __builtin_amdgcn_mfma_f32_16x16x32_bf16(
                    as_bf16x8(*(const u32x4a*)&s_w[((26 + nt * 2 + 1) * 64 + lane) * 8]), h1, acc, 0, 0, 0);
                u32x2 pk = {cvt_pk_bf16(softplus_f(acc[0]), softplus_f(acc[1])),
                            cvt_pk_bf16(softplus_f(acc[2]), softplus_f(acc[3]))};
                *(u32x2a*)&hw[c * 72 + nt * 16 + q * 4] = pk;
            }
        }
        // ---- rgb layer 2: K=64, outs 0..2 (sigmoid) + epilogue ----
        {
            bf16x8 h0 = as_bf16x8(*(const u32x4a*)&hw[c * 72 + 0 + q * 8]);
            bf16x8 h1 = as_bf16x8(*(const u32x4a*)&hw[c * 72 + 32 + q * 8]);
            f32x4 acc = *(const f32x4a*)&s_bias[208 + q * 4];
            acc = __builtin_amdgcn_mfma_f32_16x16x32_bf16(
                as_bf16x8(*(const u32x4a*)&s_w[(34 * 64 + lane) * 8]), h0, acc, 0, 0, 0);
            acc = __builtin_amdgcn_mfma_f32_16x16x32_bf16(
                as_bf16x8(*(const u32x4a*)&s_w[(35 * 64 + lane) * 8]), h1, acc, 0, 0, 0);
            if (q == 0) {  // lane c holds all channels of point p0+c
                f32x4 o;
                o[0] = 1.f / (1.f + __expf(-acc[0]));
                o[1] = 1.f / (1.f + __expf(-acc[1]));
                o[2] = 1.f / (1.f + __expf(-acc[2]));
                o[3] = occv;
                *(f32x4a*)&out[(p0 + c) * 4] = o;
                out[(long)4 * n + p0 + c] = occv;
            }
        }
    }
}

extern "C" void kernel_launch(void* const* d_in, const int* in_sizes, int n_in,
                              void* d_out, int out_size, void* d_ws, size_t ws_size,
                              hipStream_t stream) {
    const int n = in_sizes[0] / 32;  // N = 524288
    float*  wsf = (float*)d_ws;
    ushort* wsw = (ushort*)((char*)d_ws + 1152);
    prep_weights<<<1, 256, 0, stream>>>(
        (const float*)d_in[2], (const float*)d_in[3],
        (const float*)d_in[4], (const float*)d_in[5],
        (const float*)d_in[6], (const float*)d_in[7],
        (const float*)d_in[8], (const float*)d_in[9],
        (const float*)d_in[10], (const float*)d_in[11],
        (const float*)d_in[12], (const float*)d_in[13],
        (const float*)d_in[14], (const int*)d_in[15],
        wsf, wsw);
    net_mfma<<<n / 1024, 512, 0, stream>>>(
        (const float*)d_in[0], (const float*)d_in[1],
        wsf, wsw, (float*)d_out, n);
}

// Round 5
// 195.350 us; speedup vs baseline: 16.8712x; 1.2055x over previous
//
#include <hip/hip_runtime.h>

typedef __bf16 bf16x8 __attribute__((ext_vector_type(8)));
typedef float f32x4 __attribute__((ext_vector_type(4)));
typedef unsigned int u32x4 __attribute__((ext_vector_type(4)));
typedef unsigned int u32x2 __attribute__((ext_vector_type(2)));
typedef u32x4 u32x4a __attribute__((may_alias));
typedef u32x2 u32x2a __attribute__((may_alias));
typedef f32x4 f32x4a __attribute__((may_alias));
typedef unsigned int u32a __attribute__((may_alias));

#define NITER 8  // iters per wave; 512-thread block => 8 waves * 16 pts * 8 = 1024 pts/block

__device__ inline unsigned short f2b(float f) {  // f32 -> bf16 RNE (prep only)
    unsigned int x;
    __builtin_memcpy(&x, &f, 4);
    unsigned int r = (x + 0x7FFFu + ((x >> 16) & 1u)) >> 16;
    return (unsigned short)r;
}
__device__ inline unsigned int cvt_pk_bf16(float lo, float hi) {
    unsigned int r;
    asm("v_cvt_pk_bf16_f32 %0, %1, %2" : "=v"(r) : "v"(lo), "v"(hi));
    return r;
}
__device__ inline float vexp2(float x) { float r; asm("v_exp_f32 %0, %1" : "=v"(r) : "v"(x)); return r; }
__device__ inline float vlog2(float x) { float r; asm("v_log_f32 %0, %1" : "=v"(r) : "v"(x)); return r; }
__device__ inline float vrcp(float x)  { float r; asm("v_rcp_f32 %0, %1" : "=v"(r) : "v"(x)); return r; }
// softplus(x) = ln2 * log2(1 + 2^(x*log2e)) — 5 inst, 2 transcendental, f32-safe for |x|<80
__device__ inline float softplus_f(float x) {
    return 0.69314718f * vlog2(1.f + vexp2(1.44269504f * x));
}
__device__ inline float sigmoid_f(float x) {
    return vrcp(1.f + vexp2(-1.44269504f * x));
}
__device__ inline bf16x8 as_bf16x8(u32x4 v) { return __builtin_bit_cast(bf16x8, v); }

// ws layout: [0..287] f32 biases | byte 1152: ushort frag-major weights 36*64*8
// bias map: [0]ob0 [64]ob1 [128]ob2 [144]rb1 [208]rb2(pad->16) [224]rgb_b0'(folded latent)
// frag bases: occ0:0(Nt4,Kt1) occ1:4(4,2) occ2:12(1,2) rgb0:14(4,3) rgb1:26(4,2) rgb2:34(1,2)
// frag: lane l holds W[k=kt*32+(l>>4)*8+j][n=nt*16+(l&15)]
// rgb0 x-row map: k<32 emb, 32..58 dir(rows 32..58), 59..63 zero,
//                 64..95 feat tile: k-local kl=1..15 -> W row 58+kl, kl=0 & kl>=16 -> ZERO
//                 (feat k-index == raw occ2 output index; out0=occ-preact nulled by zero row)

__global__ __launch_bounds__(256) void prep_weights(
    const float* __restrict__ oW0, const float* __restrict__ ob0,
    const float* __restrict__ oW1, const float* __restrict__ ob1,
    const float* __restrict__ oW2, const float* __restrict__ ob2,
    const float* __restrict__ rW0, const float* __restrict__ rb0,
    const float* __restrict__ rW1, const float* __restrict__ rb1,
    const float* __restrict__ rW2, const float* __restrict__ rb2,
    const float* __restrict__ rlat, const int* __restrict__ lidx,
    float* __restrict__ wsf, ushort* __restrict__ wsw)
{
    const int bid = blockIdx.x, tid = threadIdx.x;
    __shared__ float red[256];

    if (bid == 0) {  // plain biases
        for (int i = tid; i < 224; i += 256) {
            float v;
            if (i < 64)       v = ob0[i];
            else if (i < 128) v = ob1[i - 64];
            else if (i < 144) v = ob2[i - 128];
            else if (i < 208) v = rb1[i - 144];
            else              v = (i - 208 < 3) ? rb2[i - 208] : 0.f;
            wsf[i] = v;
        }
    }
    if (bid == 7) {  // parallel latent fold: rgb_b0' = rgb_b0 + latent @ rgb_W0[74:202]
        const int outn = tid & 63, sl = tid >> 6;  // 4 slices x 32 k
        const float* lat = rlat + (size_t)lidx[0] * 128;
        float p = 0.f;
        for (int k = sl * 32; k < sl * 32 + 32; k++)
            p = fmaf(lat[k], rW0[(74 + k) * 64 + outn], p);
        red[tid] = p;
        __syncthreads();
        if (tid < 64)
            wsf[224 + tid] = rb0[tid] + red[tid] + red[64 + tid] + red[128 + tid] + red[192 + tid];
    }
    // fragment-major weight table: 2304 frag-lanes split across 8 blocks
    for (int t = tid; t < 288; t += 256) {
        const int s = bid * 288 + t;
        const int frag = s >> 6, lane = s & 63;
        const int qq = lane >> 4, cc = lane & 15;
        const float* W;
        int ldn = 64, nt = 0, kt = 0;
        bool isr0 = false, isr2 = false;
        if (frag < 4)       { W = oW0; nt = frag; kt = 0; }
        else if (frag < 12) { W = oW1; int f = frag - 4;  nt = f >> 1; kt = f & 1; }
        else if (frag < 14) { W = oW2; ldn = 16; nt = 0; kt = frag - 12; }
        else if (frag < 26) { W = rW0; int f = frag - 14; nt = f / 3; kt = f - nt * 3; isr0 = true; }
        else if (frag < 34) { W = rW1; int f = frag - 26; nt = f >> 1; kt = f & 1; }
        else                { W = rW2; ldn = 3; nt = 0; kt = frag - 34; isr2 = true; }
        const int nn = nt * 16 + cc;
        __align__(16) ushort vals[8];
#pragma unroll
        for (int j = 0; j < 8; j++) {
            int k = kt * 32 + qq * 8 + j;
            float v = 0.f;
            if (isr0) {
                int ks = -1;
                if (k < 59) ks = k;                            // emb + dir rows
                else if (k >= 65 && k < 80) ks = k - 65 + 59;  // feat kl=1..15 -> rows 59..73
                if (ks >= 0) v = W[ks * 64 + nn];
            } else if (isr2) {
                if (nn < 3) v = W[k * 3 + nn];
            } else {
                v = W[k * ldn + nn];
            }
            vals[j] = f2b(v);
        }
        *(u32x4a*)&wsw[s * 8] = *(const u32x4a*)vals;
    }
}

// Transposed-compute kernel: D = W^T_tile · X^T_tile  (row=out, col=point).
// Lane (q=l>>4, c=l&15) holds outs nt*16+q*4+{0..3} of point c -> packed b64 writes.
__global__ __launch_bounds__(512, 4) void net_mfma(
    const float* __restrict__ emb, const float* __restrict__ dir,
    const float* __restrict__ wsf, const ushort* __restrict__ wsw,
    float* __restrict__ out, int n)
{
    __shared__ __align__(16) ushort s_w[36 * 64 * 8];    // 36,864 B
    __shared__ __align__(16) ushort s_h[8][16 * 72];     // 18,432 B  activations, ld=72

    const int tid = threadIdx.x;
    for (int i = tid; i < 36 * 64; i += 512)
        *(u32x4a*)&s_w[i * 8] = *(const u32x4a*)(wsw + i * 8);
    __syncthreads();

    const int wave = tid >> 6, lane = tid & 63, q = lane >> 4, c = lane & 15;
    ushort* hw = s_h[wave];
    // zero own activation slice once (garbage LDS could be NaN-patterned bf16)
    for (int i = lane; i < 576; i += 64) ((u32a*)hw)[i] = 0u;

    // ---- biases resident in VGPRs (18 x f32x4 = 72 VGPRs) ----
    const int q4 = q * 4;
    f32x4 Bv[18];
#pragma unroll
    for (int nt = 0; nt < 4; nt++) {
        Bv[0 + nt]  = *(const f32x4a*)(wsf + 0   + nt * 16 + q4);  // occ0
        Bv[4 + nt]  = *(const f32x4a*)(wsf + 64  + nt * 16 + q4);  // occ1
        Bv[9 + nt]  = *(const f32x4a*)(wsf + 224 + nt * 16 + q4);  // rgb0'
        Bv[13 + nt] = *(const f32x4a*)(wsf + 144 + nt * 16 + q4);  // rgb1
    }
    Bv[8]  = *(const f32x4a*)(wsf + 128 + q4);  // occ2
    Bv[17] = *(const f32x4a*)(wsf + 208 + q4);  // rgb2

    const long dlim = (long)n * 27;

    for (int it = 0; it < NITER; ++it) {
        const long p0 = (long)blockIdx.x * 1024 + it * 128 + wave * 16;  // +c = point

        // ---- input B-fragments straight from global ----
        bf16x8 x_emb, x_dir;
        {
            const float* ep = emb + (p0 + c) * 32 + q * 8;
            f32x4 e0 = *(const f32x4a*)ep;
            f32x4 e1 = *(const f32x4a*)(ep + 4);
            u32x4 pk = {cvt_pk_bf16(e0[0], e0[1]), cvt_pk_bf16(e0[2], e0[3]),
                        cvt_pk_bf16(e1[0], e1[1]), cvt_pk_bf16(e1[2], e1[3])};
            x_emb = as_bf16x8(pk);
        }
        {
            const long ib = (p0 + c) * 27 + q * 8;
            f32x4 d0, d1;
            if (ib + 8 <= dlim) {          // all but one wave in the grid
                d0 = *(const f32x4a*)(dir + ib);
                d1 = *(const f32x4a*)(dir + ib + 4);
            } else {                       // final point, q=3: guard OOB
#pragma unroll
                for (int j = 0; j < 4; j++) d0[j] = (ib + j < dlim) ? dir[ib + j] : 0.f;
#pragma unroll
                for (int j = 0; j < 4; j++) d1[j] = (ib + 4 + j < dlim) ? dir[ib + 4 + j] : 0.f;
            }
            // k-local >= 27 lanes carry garbage; rgb0 dir weight rows 27..31 are zero
            u32x4 pk = {cvt_pk_bf16(d0[0], d0[1]), cvt_pk_bf16(d0[2], d0[3]),
                        cvt_pk_bf16(d1[0], d1[1]), cvt_pk_bf16(d1[2], d1[3])};
            x_dir = as_bf16x8(pk);
        }

        // ---- occ layer 0: K=32 (emb), out 64 ----
#pragma unroll
        for (int nt = 0; nt < 4; ++nt) {
            f32x4 acc = Bv[0 + nt];
            acc = __builtin_amdgcn_mfma_f32_16x16x32_bf16(
                as_bf16x8(*(const u32x4a*)&s_w[((0 + nt) * 64 + lane) * 8]), x_emb, acc, 0, 0, 0);
            u32x2 pk = {cvt_pk_bf16(softplus_f(acc[0]), softplus_f(acc[1])),
                        cvt_pk_bf16(softplus_f(acc[2]), softplus_f(acc[3]))};
            *(u32x2a*)&hw[c * 72 + nt * 16 + q4] = pk;
        }
        // ---- occ layer 1: K=64, out 64 ----
        {
            bf16x8 h0 = as_bf16x8(*(const u32x4a*)&hw[c * 72 + 0 + q * 8]);
            bf16x8 h1 = as_bf16x8(*(const u32x4a*)&hw[c * 72 + 32 + q * 8]);
#pragma unroll
            for (int nt = 0; nt < 4; ++nt) {
                f32x4 acc = Bv[4 + nt];
                acc = __builtin_amdgcn_mfma_f32_16x16x32_bf16(
                    as_bf16x8(*(const u32x4a*)&s_w[((4 + nt * 2 + 0) * 64 + lane) * 8]), h0, acc, 0, 0, 0);
                acc = __builtin_amdgcn_mfma_f32_16x16x32_bf16(
                    as_bf16x8(*(const u32x4a*)&s_w[((4 + nt * 2 + 1) * 64 + lane) * 8]), h1, acc, 0, 0, 0);
                u32x2 pk = {cvt_pk_bf16(softplus_f(acc[0]), softplus_f(acc[1])),
                            cvt_pk_bf16(softplus_f(acc[2]), softplus_f(acc[3]))};
                *(u32x2a*)&hw[c * 72 + nt * 16 + q4] = pk;
            }
        }
        // ---- occ layer 2: K=64, out 16 (raw outs -> feat region k=0..15; occ = sigmoid(out0)) ----
        float occv;
        {
            bf16x8 h0 = as_bf16x8(*(const u32x4a*)&hw[c * 72 + 0 + q * 8]);
            bf16x8 h1 = as_bf16x8(*(const u32x4a*)&hw[c * 72 + 32 + q * 8]);
            f32x4 acc = Bv[8];
            acc = __builtin_amdgcn_mfma_f32_16x16x32_bf16(
                as_bf16x8(*(const u32x4a*)&s_w[(12 * 64 + lane) * 8]), h0, acc, 0, 0, 0);
            acc = __builtin_amdgcn_mfma_f32_16x16x32_bf16(
                as_bf16x8(*(const u32x4a*)&s_w[(13 * 64 + lane) * 8]), h1, acc, 0, 0, 0);
            occv = sigmoid_f(acc[0]);  // 1-exp(-softplus(h)) == sigmoid(h); valid on q==0
            u32x2 pk = {cvt_pk_bf16(acc[0], acc[1]), cvt_pk_bf16(acc[2], acc[3])};
            *(u32x2a*)&hw[c * 72 + q4] = pk;  // raw outs 0..15 (out0 nulled by zero weight row)
        }
        // ---- rgb layer 0: K=96 (emb|dir|feat), out 64, bias = folded rgb_b0' ----
        {
            // q>=2 reads stale h (k-local 16..31): finite garbage x zero weight rows
            bf16x8 x_feat = as_bf16x8(*(const u32x4a*)&hw[c * 72 + q * 8]);
#pragma unroll
            for (int nt = 0; nt < 4; ++nt) {
                f32x4 acc = Bv[9 + nt];
                acc = __builtin_amdgcn_mfma_f32_16x16x32_bf16(
                    as_bf16x8(*(const u32x4a*)&s_w[((14 + nt * 3 + 0) * 64 + lane) * 8]), x_emb, acc, 0, 0, 0);
                acc = __builtin_amdgcn_mfma_f32_16x16x32_bf16(
                    as_bf16x8(*(const u32x4a*)&s_w[((14 + nt * 3 + 1) * 64 + lane) * 8]), x_dir, acc, 0, 0, 0);
                acc = __builtin_amdgcn_mfma_f32_16x16x32_bf16(
                    as_bf16x8(*(const u32x4a*)&s_w[((14 + nt * 3 + 2) * 64 + lane) * 8]), x_feat, acc, 0, 0, 0);
                u32x2 pk = {cvt_pk_bf16(softplus_f(acc[0]), softplus_f(acc[1])),
                            cvt_pk_bf16(softplus_f(acc[2]), softplus_f(acc[3]))};
                *(u32x2a*)&hw[c * 72 + nt * 16 + q4] = pk;
            }
        }
        // ---- rgb layer 1: K=64, out 64 ----
        {
            bf16x8 h0 = as_bf16x8(*(const u32x4a*)&hw[c * 72 + 0 + q * 8]);
            bf16x8 h1 = as_bf16x8(*(const u32x4a*)&hw[c * 72 + 32 + q * 8]);
#pragma unroll
            for (int nt = 0; nt < 4; ++nt) {
                f32x4 acc = Bv[13 + nt];
                acc = __builtin_amdgcn_mfma_f32_16x16x32_bf16(
                    as_bf16x8(*(const u32x4a*)&s_w[((26 + nt * 2 + 0) * 64 + lane) * 8]), h0, acc, 0, 0, 0);
                acc = __builtin_amdgcn_mfma_f32_16x16x32_bf16(
                    as_bf16x8(*(const u32x4a*)&s_w[((26 + nt * 2 + 1) * 64 + lane) * 8]), h1, acc, 0, 0, 0);
                u32x2 pk = {cvt_pk_bf16(softplus_f(acc[0]), softplus_f(acc[1])),
                            cvt_pk_bf16(softplus_f(acc[2]), softplus_f(acc[3]))};
                *(u32x2a*)&hw[c * 72 + nt * 16 + q4] = pk;
            }
        }
        // ---- rgb layer 2: K=64, outs 0..2 (sigmoid) + epilogue ----
        {
            bf16x8 h0 = as_bf16x8(*(const u32x4a*)&hw[c * 72 + 0 + q * 8]);
            bf16x8 h1 = as_bf16x8(*(const u32x4a*)&hw[c * 72 + 32 + q * 8]);
            f32x4 acc = Bv[17];
            acc = __builtin_amdgcn_mfma_f32_16x16x32_bf16(
                as_bf16x8(*(const u32x4a*)&s_w[(34 * 64 + lane) * 8]), h0, acc, 0, 0, 0);
            acc = __builtin_amdgcn_mfma_f32_16x16x32_bf16(
                as_bf16x8(*(const u32x4a*)&s_w[(35 * 64 + lane) * 8]), h1, acc, 0, 0, 0);
            if (q == 0) {  // lane c holds all channels of point p0+c
                f32x4 o;
                o[0] = sigmoid_f(acc[0]);
                o[1] = sigmoid_f(acc[1]);
                o[2] = sigmoid_f(acc[2]);
                o[3] = occv;
                *(f32x4a*)&out[(p0 + c) * 4] = o;
                out[(long)4 * n + p0 + c] = occv;
            }
        }
    }
}

extern "C" void kernel_launch(void* const* d_in, const int* in_sizes, int n_in,
                              void* d_out, int out_size, void* d_ws, size_t ws_size,
                              hipStream_t stream) {
    const int n = in_sizes[0] / 32;  // N = 524288
    float*  wsf = (float*)d_ws;
    ushort* wsw = (ushort*)((char*)d_ws + 1152);
    prep_weights<<<8, 256, 0, stream>>>(
        (const float*)d_in[2], (const float*)d_in[3],
        (const float*)d_in[4], (const float*)d_in[5],
        (const float*)d_in[6], (const float*)d_in[7],
        (const float*)d_in[8], (const float*)d_in[9],
        (const float*)d_in[10], (const float*)d_in[11],
        (const float*)d_in[12], (const float*)d_in[13],
        (const float*)d_in[14], (const int*)d_in[15],
        wsf, wsw);
    net_mfma<<<n / 1024, 512, 0, stream>>>(
        (const float*)d_in[0], (const float*)d_in[1],
        wsf, wsw, (float*)d_out, n);
}